// Round 5
// baseline (381.823 us; speedup 1.0000x reference)
//
#include <hip/hip_runtime.h>

#define FD 128            // feature dim
#define HD 64             // hidden per MLP
#define NC 128            // combined cols (64 MLP-a | 64 MLP-n)
#define RPB 64            // nodes per tile
#define NPROD 6           // producer waves (of 8)
#define NBLK 512

typedef __attribute__((ext_vector_type(8))) short bf16x8;
typedef __attribute__((ext_vector_type(4))) float f32x4;

__device__ __forceinline__ unsigned bfr(float x) {
    unsigned u = __float_as_uint(x);
    return (u + 0x7fffu + ((u >> 16) & 1u)) >> 16;
}

// Fold LN affine into first-layer weights (bf16, transposed); LN bias into layer bias.
__global__ void prep_kernel(
    const float* __restrict__ lnag, const float* __restrict__ lnab,
    const float* __restrict__ Wa1, const float* __restrict__ ba1, const float* __restrict__ Wa2,
    const float* __restrict__ lnng, const float* __restrict__ lnnb,
    const float* __restrict__ Wn1, const float* __restrict__ bn1, const float* __restrict__ Wn2,
    unsigned short* __restrict__ wq, float* __restrict__ c, float* __restrict__ w2)
{
    int n = threadIdx.x;  // 0..127
    const float* W  = (n < HD) ? Wa1 : Wn1;
    const float* g  = (n < HD) ? lnag : lnng;
    const float* bb = (n < HD) ? lnab : lnnb;
    const float* b1 = (n < HD) ? ba1 : bn1;
    const float* W2 = (n < HD) ? Wa2 : Wn2;
    int h = n & (HD - 1);
    float accb = b1[h];
    for (int f = 0; f < FD; ++f) {
        float w = W[f * HD + h];
        wq[n * FD + f] = (unsigned short)bfr(g[f] * w);
        accb += bb[f] * w;
    }
    c[n] = accb;
    w2[n] = W2[h];
}

// ---- producer: t for one 64-node tile -> tslot[64] (LDS) ----
__device__ __forceinline__ void produce_tile(
    int tilebase, float* __restrict__ tslot,
    const float* __restrict__ vec, const float4 wn,
    const float* __restrict__ pos, const float* __restrict__ mc,
    const int* __restrict__ bidx, int n_nodes, int hw, int j)
{
    for (int slot = hw; slot < RPB; slot += 2 * NPROD) {
        int node = tilebase + slot;
        bool valid = node < n_nodes;
        int n = valid ? node : (n_nodes - 1);
        const float4* vr = reinterpret_cast<const float4*>(vec + (size_t)n * 3 * FD);
        float4 v0 = vr[j], v1 = vr[32 + j], v2 = vr[64 + j];
        int b = bidx[n];
        float m0 = pos[n * 3 + 0] - mc[b * 3 + 0];
        float m1 = pos[n * 3 + 1] - mc[b * 3 + 1];
        float m2 = pos[n * 3 + 2] - mc[b * 3 + 2];
        float acc = (v0.x * wn.x + v0.y * wn.y + v0.z * wn.z + v0.w * wn.w) * m0
                  + (v1.x * wn.x + v1.y * wn.y + v1.z * wn.z + v1.w * wn.w) * m1
                  + (v2.x * wn.x + v2.y * wn.y + v2.z * wn.z + v2.w * wn.w) * m2;
#pragma unroll
        for (int off = 16; off; off >>= 1) acc += __shfl_xor(acc, off);
        if (j == 0 && valid) tslot[slot] = acc;
    }
}

// ---- consumer: LN + MFMA + SiLU + dot + scatter for one tile ----
__device__ __forceinline__ void consume_tile(
    int tilebase, const float* __restrict__ tslot, uint4* __restrict__ xs,
    const float* __restrict__ scaler, const unsigned short* __restrict__ wq,
    const float* __restrict__ c, const float* __restrict__ w2,
    float b2a, float b2n, const int* __restrict__ bidx,
    float* __restrict__ out, int n_nodes, int cw, int lane)
{
    int r16 = lane >> 2, qd = lane & 3;           // 4 lanes/row, 16 rows/group
    // X: scaler -> LN -> bf16 -> LDS (two groups of 16 rows per wave)
#pragma unroll
    for (int g = 0; g < 2; ++g) {
        int row = cw * 32 + g * 16 + r16;
        int node = tilebase + row;
        int gn = node < n_nodes ? node : (n_nodes - 1);
        const float4* rp = reinterpret_cast<const float4*>(scaler + (size_t)gn * FD) + qd * 8;
        float4 v[8];
        float s = 0.f, s2 = 0.f;
#pragma unroll
        for (int i = 0; i < 8; ++i) {
            v[i] = rp[i];
            s  += v[i].x + v[i].y + v[i].z + v[i].w;
            s2 += v[i].x * v[i].x + v[i].y * v[i].y + v[i].z * v[i].z + v[i].w * v[i].w;
        }
        s  += __shfl_xor(s, 1);  s  += __shfl_xor(s, 2);
        s2 += __shfl_xor(s2, 1); s2 += __shfl_xor(s2, 2);
        float mu = s * (1.f / FD);
        float var = s2 * (1.f / FD) - mu * mu;
        float rstd = rsqrtf(var + 1e-5f);
#pragma unroll
        for (int jj = 0; jj < 4; ++jj) {
            float4 a = v[2 * jj], b = v[2 * jj + 1];
            uint4 pk;
            pk.x = bfr((a.x - mu) * rstd) | (bfr((a.y - mu) * rstd) << 16);
            pk.y = bfr((a.z - mu) * rstd) | (bfr((a.w - mu) * rstd) << 16);
            pk.z = bfr((b.x - mu) * rstd) | (bfr((b.y - mu) * rstd) << 16);
            pk.w = bfr((b.z - mu) * rstd) | (bfr((b.w - mu) * rstd) << 16);
            int slot = qd * 4 + jj;
            xs[row * 16 + (slot ^ (row & 15))] = pk;
        }
    }
    // MFMA: this wave's 32 rows x 128 cols, K=128 (B-frags from L1/L2-resident wq)
    int lrow = lane & 15, lgrp = lane >> 4;
    bf16x8 af0[4], af1[4];
    int r0 = cw * 32 + lrow, r1 = r0 + 16;
#pragma unroll
    for (int ks = 0; ks < 4; ++ks) {
        af0[ks] = *reinterpret_cast<const bf16x8*>(&xs[r0 * 16 + ((ks * 4 + lgrp) ^ (r0 & 15))]);
        af1[ks] = *reinterpret_cast<const bf16x8*>(&xs[r1 * 16 + ((ks * 4 + lgrp) ^ (r1 & 15))]);
    }
    float pa0[4] = {0,0,0,0}, pn0[4] = {0,0,0,0}, pa1[4] = {0,0,0,0}, pn1[4] = {0,0,0,0};
#pragma unroll
    for (int tc = 0; tc < 8; ++tc) {
        f32x4 a0 = {0.f,0.f,0.f,0.f}, a1 = {0.f,0.f,0.f,0.f};
        int n = tc * 16 + lrow;
        const bf16x8* brow = reinterpret_cast<const bf16x8*>(wq + n * FD);
#pragma unroll
        for (int ks = 0; ks < 4; ++ks) {
            bf16x8 bf = brow[ks * 4 + lgrp];
            a0 = __builtin_amdgcn_mfma_f32_16x16x32_bf16(af0[ks], bf, a0, 0, 0, 0);
            a1 = __builtin_amdgcn_mfma_f32_16x16x32_bf16(af1[ks], bf, a1, 0, 0, 0);
        }
        int col = tc * 16 + lrow;
        float bias = c[col], w2v = w2[col];
#pragma unroll
        for (int r = 0; r < 4; ++r) {
            float h0 = a0[r] + bias, h1 = a1[r] + bias;
            float y0 = h0 / (1.f + __expf(-h0));
            float y1 = h1 / (1.f + __expf(-h1));
            if (tc < 4) { pa0[r] += y0 * w2v; pa1[r] += y1 * w2v; }
            else        { pn0[r] += y0 * w2v; pn1[r] += y1 * w2v; }
        }
    }
#pragma unroll
    for (int off = 1; off < 16; off <<= 1) {
#pragma unroll
        for (int r = 0; r < 4; ++r) {
            pa0[r] += __shfl_xor(pa0[r], off);
            pn0[r] += __shfl_xor(pn0[r], off);
            pa1[r] += __shfl_xor(pa1[r], off);
            pn1[r] += __shfl_xor(pn1[r], off);
        }
    }
    if (lrow == 0) {
#pragma unroll
        for (int r = 0; r < 4; ++r) {
            int row = cw * 32 + lgrp * 4 + r;
            int node = tilebase + row;
            if (node < n_nodes) {
                float val = (pa0[r] + b2a) + (2.f / 3.f) * (pn0[r] + b2n) * tslot[row];
                atomicAdd(out + bidx[node], val);
            }
            int rowb = row + 16, nodeb = node + 16;
            if (nodeb < n_nodes) {
                float val = (pa1[r] + b2a) + (2.f / 3.f) * (pn1[r] + b2n) * tslot[rowb];
                atomicAdd(out + bidx[nodeb], val);
            }
        }
    }
}

__global__ __launch_bounds__(512, 1) void fused_kernel(
    const float* __restrict__ scaler, const float* __restrict__ vec,
    const float* __restrict__ wnu, const float* __restrict__ pos,
    const float* __restrict__ mc, const int* __restrict__ bidx,
    const unsigned short* __restrict__ wq, const float* __restrict__ c,
    const float* __restrict__ w2, const float* __restrict__ ba2,
    const float* __restrict__ bn2, float* __restrict__ out,
    int n_nodes, int ntiles, int nblocks)
{
    __shared__ uint4 xs[RPB * 16];   // 16 KiB (consumer-private rows)
    __shared__ float tl[2][RPB];

    int tid = threadIdx.x;
    int lane = tid & 63;
    int wid = tid >> 6;

    int t0 = (int)(((long long)blockIdx.x * ntiles) / nblocks);
    int t1 = (int)(((long long)(blockIdx.x + 1) * ntiles) / nblocks);
    int m = t1 - t0;
    if (m <= 0) return;

    if (wid < NPROD) {
        int hw = wid * 2 + (lane >> 5);
        int j = lane & 31;
        float4 wn = reinterpret_cast<const float4*>(wnu)[j];
        produce_tile(t0 * RPB, tl[0], vec, wn, pos, mc, bidx, n_nodes, hw, j);
        __syncthreads();
        for (int k = 0; k < m; ++k) {
            if (k + 1 < m)
                produce_tile((t0 + k + 1) * RPB, tl[(k + 1) & 1], vec, wn, pos, mc, bidx,
                             n_nodes, hw, j);
            __syncthreads();
        }
    } else {
        int cw = wid - NPROD;
        float b2a = ba2[0], b2n = bn2[0];
        __syncthreads();
        for (int k = 0; k < m; ++k) {
            consume_tile((t0 + k) * RPB, tl[k & 1], xs, scaler, wq, c, w2,
                         b2a, b2n, bidx, out, n_nodes, cw, lane);
            __syncthreads();
        }
    }
}

extern "C" void kernel_launch(void* const* d_in, const int* in_sizes, int n_in,
                              void* d_out, int out_size, void* d_ws, size_t ws_size,
                              hipStream_t stream) {
    const float* pos    = (const float*)d_in[0];
    const float* mc     = (const float*)d_in[1];
    const float* scaler = (const float*)d_in[2];
    const float* vec    = (const float*)d_in[3];
    const int*   bidx   = (const int*)d_in[4];
    const float* lnag   = (const float*)d_in[5];
    const float* lnab   = (const float*)d_in[6];
    const float* Wa1    = (const float*)d_in[7];
    const float* ba1    = (const float*)d_in[8];
    const float* Wa2    = (const float*)d_in[9];
    const float* ba2    = (const float*)d_in[10];
    const float* lnng   = (const float*)d_in[11];
    const float* lnnb   = (const float*)d_in[12];
    const float* Wn1    = (const float*)d_in[13];
    const float* bn1    = (const float*)d_in[14];
    const float* Wn2    = (const float*)d_in[15];
    const float* bn2    = (const float*)d_in[16];
    const float* Wnu    = (const float*)d_in[17];

    int N = in_sizes[0] / 3;
    int B = in_sizes[1] / 3;

    unsigned short* wq = (unsigned short*)d_ws;            // NC*FD bf16 = 32 KiB
    float* c  = (float*)((char*)d_ws + NC * FD * 2);       // 128 f32
    float* w2 = c + NC;                                    // 128 f32

    hipMemsetAsync(d_out, 0, (size_t)B * sizeof(float), stream);

    hipLaunchKernelGGL(prep_kernel, dim3(1), dim3(NC), 0, stream,
                       lnag, lnab, Wa1, ba1, Wa2, lnng, lnnb, Wn1, bn1, Wn2, wq, c, w2);

    int ntiles = (N + RPB - 1) / RPB;
    int nblocks = ntiles < NBLK ? ntiles : NBLK;
    hipLaunchKernelGGL(fused_kernel, dim3(nblocks), dim3(512), 0, stream,
                       scaler, vec, Wnu, pos, mc, bidx, wq, c, w2, ba2, bn2,
                       (float*)d_out, N, ntiles, nblocks);
}

// Round 6
// 254.494 us; speedup vs baseline: 1.5003x; 1.5003x over previous
//
#include <hip/hip_runtime.h>

#define FD 128            // feature dim
#define HD 64             // hidden per MLP
#define NC 128            // combined cols (64 MLP-a | 64 MLP-n)
#define RPB 64            // nodes per block

typedef __attribute__((ext_vector_type(8))) short bf16x8;
typedef __attribute__((ext_vector_type(4))) float f32x4;

__device__ __forceinline__ unsigned bfr(float x) {
    unsigned u = __float_as_uint(x);
    return (u + 0x7fffu + ((u >> 16) & 1u)) >> 16;
}

// Fold LN affine into first-layer weights (bf16, transposed); LN bias into layer bias.
__global__ void prep_kernel(
    const float* __restrict__ lnag, const float* __restrict__ lnab,
    const float* __restrict__ Wa1, const float* __restrict__ ba1, const float* __restrict__ Wa2,
    const float* __restrict__ lnng, const float* __restrict__ lnnb,
    const float* __restrict__ Wn1, const float* __restrict__ bn1, const float* __restrict__ Wn2,
    unsigned short* __restrict__ wq, float* __restrict__ c, float* __restrict__ w2)
{
    int n = threadIdx.x;  // 0..127
    const float* W  = (n < HD) ? Wa1 : Wn1;
    const float* g  = (n < HD) ? lnag : lnng;
    const float* bb = (n < HD) ? lnab : lnnb;
    const float* b1 = (n < HD) ? ba1 : bn1;
    const float* W2 = (n < HD) ? Wa2 : Wn2;
    int h = n & (HD - 1);
    float accb = b1[h];
    for (int f = 0; f < FD; ++f) {
        float w = W[f * HD + h];
        wq[n * FD + f] = (unsigned short)bfr(g[f] * w);
        accb += bb[f] * w;
    }
    c[n] = accb;
    w2[n] = W2[h];
}

// Fused, one 64-node tile per 256-thread block.
// T phase: 8 lanes per node (12 float4 each, k<4:d0, k<8:d1, else d2), 3-shfl octet reduce.
// X phase: LN -> bf16 -> swizzled LDS. MFMA: [64x128]@[128x128], B-frags from L2-resident wq.
__global__ __launch_bounds__(256, 4) void fused_kernel(
    const float* __restrict__ scaler, const float* __restrict__ vec,
    const float* __restrict__ wnu, const float* __restrict__ pos,
    const float* __restrict__ mc, const int* __restrict__ bidx,
    const unsigned short* __restrict__ wq, const float* __restrict__ c,
    const float* __restrict__ w2, const float* __restrict__ ba2,
    const float* __restrict__ bn2, float* __restrict__ out, int n_nodes)
{
    __shared__ uint4 xs[RPB * 16];   // 16 KiB, XOR-swizzled
    __shared__ float tl[RPB];

    int tid = threadIdx.x;
    int rowbase = blockIdx.x * RPB;
    int lane = tid & 63, w = tid >> 6;

    // ---- phase T: vector contraction, 8 lanes per node ----
    {
        int o = lane >> 3, cc = lane & 7;
        float4 wn4[4];
#pragma unroll
        for (int m = 0; m < 4; ++m)
            wn4[m] = reinterpret_cast<const float4*>(wnu)[m * 8 + cc];
#pragma unroll
        for (int g = 0; g < 2; ++g) {
            int row = w * 16 + g * 8 + o;
            int node = rowbase + row;
            bool valid = node < n_nodes;
            int n = valid ? node : (n_nodes - 1);
            int b = bidx[n];
            float m0 = pos[n * 3 + 0] - mc[b * 3 + 0];
            float m1 = pos[n * 3 + 1] - mc[b * 3 + 1];
            float m2 = pos[n * 3 + 2] - mc[b * 3 + 2];
            const float4* vr = reinterpret_cast<const float4*>(vec + (size_t)n * 3 * FD);
            float acc = 0.f;
#pragma unroll
            for (int k = 0; k < 12; ++k) {
                float4 v = vr[cc + k * 8];
                float4 wnv = wn4[k & 3];
                float d4 = v.x * wnv.x + v.y * wnv.y + v.z * wnv.z + v.w * wnv.w;
                float mm = (k < 4) ? m0 : (k < 8 ? m1 : m2);
                acc = fmaf(d4, mm, acc);
            }
            acc += __shfl_xor(acc, 1);
            acc += __shfl_xor(acc, 2);
            acc += __shfl_xor(acc, 4);
            if (cc == 0 && valid) tl[row] = acc;
        }
    }

    // ---- phase X: scaler + LN -> bf16 LDS ----
    {
        int r = tid >> 2, qd = tid & 3;           // 4 lanes per row, 32 floats each
        int node = rowbase + r;
        int gn = node < n_nodes ? node : (n_nodes - 1);
        const float4* rp = reinterpret_cast<const float4*>(scaler + (size_t)gn * FD) + qd * 8;
        float4 v[8];
        float s = 0.f, s2 = 0.f;
#pragma unroll
        for (int i = 0; i < 8; ++i) {
            v[i] = rp[i];
            s  += v[i].x + v[i].y + v[i].z + v[i].w;
            s2 += v[i].x * v[i].x + v[i].y * v[i].y + v[i].z * v[i].z + v[i].w * v[i].w;
        }
        s  += __shfl_xor(s, 1);  s  += __shfl_xor(s, 2);
        s2 += __shfl_xor(s2, 1); s2 += __shfl_xor(s2, 2);
        float mu = s * (1.f / FD);
        float var = s2 * (1.f / FD) - mu * mu;
        float rstd = rsqrtf(var + 1e-5f);
#pragma unroll
        for (int jj = 0; jj < 4; ++jj) {
            float4 a = v[2 * jj], b = v[2 * jj + 1];
            uint4 pk;
            pk.x = bfr((a.x - mu) * rstd) | (bfr((a.y - mu) * rstd) << 16);
            pk.y = bfr((a.z - mu) * rstd) | (bfr((a.w - mu) * rstd) << 16);
            pk.z = bfr((b.x - mu) * rstd) | (bfr((b.y - mu) * rstd) << 16);
            pk.w = bfr((b.z - mu) * rstd) | (bfr((b.w - mu) * rstd) << 16);
            int slot = qd * 4 + jj;
            xs[r * 16 + (slot ^ (r & 15))] = pk;
        }
    }
    __syncthreads();

    // ---- MFMA: each wave 16 rows x 128 cols, K=128; B-frags from global wq ----
    int lrow = lane & 15, lgrp = lane >> 4;
    bf16x8 af[4];
#pragma unroll
    for (int ks = 0; ks < 4; ++ks) {
        int r = w * 16 + lrow;
        af[ks] = *reinterpret_cast<const bf16x8*>(&xs[r * 16 + ((ks * 4 + lgrp) ^ (r & 15))]);
    }
    float pa[4] = {0.f, 0.f, 0.f, 0.f}, pn[4] = {0.f, 0.f, 0.f, 0.f};
#pragma unroll
    for (int tile = 0; tile < 8; ++tile) {
        f32x4 acc = {0.f, 0.f, 0.f, 0.f};
        int n = tile * 16 + lrow;
        const bf16x8* brow = reinterpret_cast<const bf16x8*>(wq + n * FD);
#pragma unroll
        for (int ks = 0; ks < 4; ++ks) {
            bf16x8 bf = brow[ks * 4 + lgrp];
            acc = __builtin_amdgcn_mfma_f32_16x16x32_bf16(af[ks], bf, acc, 0, 0, 0);
        }
        int col = tile * 16 + lrow;
        float bias = c[col], w2v = w2[col];
#pragma unroll
        for (int r = 0; r < 4; ++r) {
            float h1 = acc[r] + bias;
            float y = h1 / (1.f + __expf(-h1));
            float cb = y * w2v;
            if (tile < 4) pa[r] += cb; else pn[r] += cb;
        }
    }
#pragma unroll
    for (int off = 1; off < 16; off <<= 1) {
#pragma unroll
        for (int r = 0; r < 4; ++r) {
            pa[r] += __shfl_xor(pa[r], off);
            pn[r] += __shfl_xor(pn[r], off);
        }
    }
    if (lrow == 0) {
        float b2a = ba2[0], b2n = bn2[0];
#pragma unroll
        for (int r = 0; r < 4; ++r) {
            int nl = w * 16 + lgrp * 4 + r;
            int node = rowbase + nl;
            if (node < n_nodes) {
                float val = (pa[r] + b2a) + (2.f / 3.f) * (pn[r] + b2n) * tl[nl];
                atomicAdd(out + bidx[node], val);
            }
        }
    }
}

extern "C" void kernel_launch(void* const* d_in, const int* in_sizes, int n_in,
                              void* d_out, int out_size, void* d_ws, size_t ws_size,
                              hipStream_t stream) {
    const float* pos    = (const float*)d_in[0];
    const float* mc     = (const float*)d_in[1];
    const float* scaler = (const float*)d_in[2];
    const float* vec    = (const float*)d_in[3];
    const int*   bidx   = (const int*)d_in[4];
    const float* lnag   = (const float*)d_in[5];
    const float* lnab   = (const float*)d_in[6];
    const float* Wa1    = (const float*)d_in[7];
    const float* ba1    = (const float*)d_in[8];
    const float* Wa2    = (const float*)d_in[9];
    const float* ba2    = (const float*)d_in[10];
    const float* lnng   = (const float*)d_in[11];
    const float* lnnb   = (const float*)d_in[12];
    const float* Wn1    = (const float*)d_in[13];
    const float* bn1    = (const float*)d_in[14];
    const float* Wn2    = (const float*)d_in[15];
    const float* bn2    = (const float*)d_in[16];
    const float* Wnu    = (const float*)d_in[17];

    int N = in_sizes[0] / 3;
    int B = in_sizes[1] / 3;

    unsigned short* wq = (unsigned short*)d_ws;            // NC*FD bf16 = 32 KiB
    float* c  = (float*)((char*)d_ws + NC * FD * 2);       // 128 f32
    float* w2 = c + NC;                                    // 128 f32

    hipMemsetAsync(d_out, 0, (size_t)B * sizeof(float), stream);

    hipLaunchKernelGGL(prep_kernel, dim3(1), dim3(NC), 0, stream,
                       lnag, lnab, Wa1, ba1, Wa2, lnng, lnnb, Wn1, bn1, Wn2, wq, c, w2);

    int blocks = (N + RPB - 1) / RPB;
    hipLaunchKernelGGL(fused_kernel, dim3(blocks), dim3(256), 0, stream,
                       scaler, vec, Wnu, pos, mc, bidx, wq, c, w2, ba2, bn2,
                       (float*)d_out, N);
}

// Round 7
// 251.350 us; speedup vs baseline: 1.5191x; 1.0125x over previous
//
#include <hip/hip_runtime.h>

#define FD 128            // feature dim
#define HD 64             // hidden per MLP
#define NC 128            // combined cols (64 MLP-a | 64 MLP-n)
#define RPB 64            // nodes per block (16 per wave)

typedef __attribute__((ext_vector_type(8))) short bf16x8;
typedef __attribute__((ext_vector_type(4))) float f32x4;

__device__ __forceinline__ unsigned bfr(float x) {
    unsigned u = __float_as_uint(x);
    return (u + 0x7fffu + ((u >> 16) & 1u)) >> 16;
}

// Fold LN affine into first-layer weights (bf16, transposed); LN bias into layer bias.
__global__ void prep_kernel(
    const float* __restrict__ lnag, const float* __restrict__ lnab,
    const float* __restrict__ Wa1, const float* __restrict__ ba1, const float* __restrict__ Wa2,
    const float* __restrict__ lnng, const float* __restrict__ lnnb,
    const float* __restrict__ Wn1, const float* __restrict__ bn1, const float* __restrict__ Wn2,
    unsigned short* __restrict__ wq, float* __restrict__ c, float* __restrict__ w2)
{
    int n = threadIdx.x;  // 0..127
    const float* W  = (n < HD) ? Wa1 : Wn1;
    const float* g  = (n < HD) ? lnag : lnng;
    const float* bb = (n < HD) ? lnab : lnnb;
    const float* b1 = (n < HD) ? ba1 : bn1;
    const float* W2 = (n < HD) ? Wa2 : Wn2;
    int h = n & (HD - 1);
    float accb = b1[h];
    for (int f = 0; f < FD; ++f) {
        float w = W[f * HD + h];
        wq[n * FD + f] = (unsigned short)bfr(g[f] * w);
        accb += bb[f] * w;
    }
    c[n] = accb;
    w2[n] = W2[h];
}

// Barrier-free fused kernel: each wave owns 16 nodes end-to-end.
//  - X: each lane loads exactly its MFMA A-fragment floats (k = ks*32+lgrp*8+j) of row lane&15,
//       LN via 2x shfl_xor(16,32) over the 4 lanes sharing a row, bf16 pack in-register.
//  - T: 8 lanes/node, 3-shfl octet reduce -> per-wave LDS strip (same-wave RAW only).
//  - MFMA [16x128]@[128x128] per wave, B-frags from L1/L2-resident wq.
//  - Epilogue: SiLU + second-layer dot + 16-lane butterfly + atomic scatter.
__global__ __launch_bounds__(256, 4) void fused_kernel(
    const float* __restrict__ scaler, const float* __restrict__ vec,
    const float* __restrict__ wnu, const float* __restrict__ pos,
    const float* __restrict__ mc, const int* __restrict__ bidx,
    const unsigned short* __restrict__ wq, const float* __restrict__ c,
    const float* __restrict__ w2, const float* __restrict__ ba2,
    const float* __restrict__ bn2, float* __restrict__ out, int n_nodes)
{
    __shared__ float tl[4][16];      // per-wave t strip

    int tid = threadIdx.x;
    int lane = tid & 63, w = tid >> 6;
    int rowbase = blockIdx.x * RPB + w * 16;   // this wave's 16 nodes
    int lrow = lane & 15, lgrp = lane >> 4;

    // ---- X loads first (straight into A-fragment registers) ----
    int xnode = rowbase + lrow;
    int gx = xnode < n_nodes ? xnode : (n_nodes - 1);
    const float4* xp = reinterpret_cast<const float4*>(scaler + (size_t)gx * FD);
    float4 xv[8];
#pragma unroll
    for (int ks = 0; ks < 4; ++ks) {
        xv[2 * ks]     = xp[ks * 8 + lgrp * 2];
        xv[2 * ks + 1] = xp[ks * 8 + lgrp * 2 + 1];
    }

    // ---- T phase: 8 lanes per node, rows 0..15 of this wave ----
    {
        int o = lane >> 3, cc = lane & 7;
        float4 wn4[4];
#pragma unroll
        for (int m = 0; m < 4; ++m)
            wn4[m] = reinterpret_cast<const float4*>(wnu)[m * 8 + cc];
#pragma unroll
        for (int g = 0; g < 2; ++g) {
            int row = g * 8 + o;
            int node = rowbase + row;
            int n = node < n_nodes ? node : (n_nodes - 1);
            int b = bidx[n];
            float m0 = pos[n * 3 + 0] - mc[b * 3 + 0];
            float m1 = pos[n * 3 + 1] - mc[b * 3 + 1];
            float m2 = pos[n * 3 + 2] - mc[b * 3 + 2];
            const float4* vr = reinterpret_cast<const float4*>(vec + (size_t)n * 3 * FD);
            float acc = 0.f;
#pragma unroll
            for (int k = 0; k < 12; ++k) {
                float4 v = vr[cc + k * 8];
                float4 wnv = wn4[k & 3];
                float d4 = v.x * wnv.x + v.y * wnv.y + v.z * wnv.z + v.w * wnv.w;
                float mm = (k < 4) ? m0 : (k < 8 ? m1 : m2);
                acc = fmaf(d4, mm, acc);
            }
            acc += __shfl_xor(acc, 1);
            acc += __shfl_xor(acc, 2);
            acc += __shfl_xor(acc, 4);
            if (cc == 0) tl[w][row] = acc;
        }
    }

    // ---- LN in-register: reduce over the 4 lanes sharing this row ----
    float s = 0.f, s2 = 0.f;
#pragma unroll
    for (int i = 0; i < 8; ++i) {
        float4 v = xv[i];
        s  += v.x + v.y + v.z + v.w;
        s2 += v.x * v.x + v.y * v.y + v.z * v.z + v.w * v.w;
    }
    s  += __shfl_xor(s, 16);  s  += __shfl_xor(s, 32);
    s2 += __shfl_xor(s2, 16); s2 += __shfl_xor(s2, 32);
    float mu = s * (1.f / FD);
    float var = s2 * (1.f / FD) - mu * mu;
    float rstd = rsqrtf(var + 1e-5f);

    bf16x8 af[4];
#pragma unroll
    for (int ks = 0; ks < 4; ++ks) {
        float4 a = xv[2 * ks], b = xv[2 * ks + 1];
        union { unsigned u[4]; bf16x8 v; } pk;
        pk.u[0] = bfr((a.x - mu) * rstd) | (bfr((a.y - mu) * rstd) << 16);
        pk.u[1] = bfr((a.z - mu) * rstd) | (bfr((a.w - mu) * rstd) << 16);
        pk.u[2] = bfr((b.x - mu) * rstd) | (bfr((b.y - mu) * rstd) << 16);
        pk.u[3] = bfr((b.z - mu) * rstd) | (bfr((b.w - mu) * rstd) << 16);
        af[ks] = pk.v;
    }

    // ---- MFMA: 16 rows x 128 cols, K=128; B-frags from global wq ----
    float pa[4] = {0.f, 0.f, 0.f, 0.f}, pn[4] = {0.f, 0.f, 0.f, 0.f};
#pragma unroll
    for (int tile = 0; tile < 8; ++tile) {
        f32x4 acc = {0.f, 0.f, 0.f, 0.f};
        int n = tile * 16 + lrow;
        const bf16x8* brow = reinterpret_cast<const bf16x8*>(wq + n * FD);
#pragma unroll
        for (int ks = 0; ks < 4; ++ks) {
            bf16x8 bf = brow[ks * 4 + lgrp];
            acc = __builtin_amdgcn_mfma_f32_16x16x32_bf16(af[ks], bf, acc, 0, 0, 0);
        }
        int col = tile * 16 + lrow;
        float bias = c[col], w2v = w2[col];
#pragma unroll
        for (int r = 0; r < 4; ++r) {
            float h1 = acc[r] + bias;
            float y = h1 / (1.f + __expf(-h1));
            float cb = y * w2v;
            if (tile < 4) pa[r] += cb; else pn[r] += cb;
        }
    }
#pragma unroll
    for (int off = 1; off < 16; off <<= 1) {
#pragma unroll
        for (int r = 0; r < 4; ++r) {
            pa[r] += __shfl_xor(pa[r], off);
            pn[r] += __shfl_xor(pn[r], off);
        }
    }
    if (lrow == 0) {
        float b2a = ba2[0], b2n = bn2[0];
#pragma unroll
        for (int r = 0; r < 4; ++r) {
            int nl = lgrp * 4 + r;
            int node = rowbase + nl;
            if (node < n_nodes) {
                float val = (pa[r] + b2a) + (2.f / 3.f) * (pn[r] + b2n) * tl[w][nl];
                atomicAdd(out + bidx[node], val);
            }
        }
    }
}

extern "C" void kernel_launch(void* const* d_in, const int* in_sizes, int n_in,
                              void* d_out, int out_size, void* d_ws, size_t ws_size,
                              hipStream_t stream) {
    const float* pos    = (const float*)d_in[0];
    const float* mc     = (const float*)d_in[1];
    const float* scaler = (const float*)d_in[2];
    const float* vec    = (const float*)d_in[3];
    const int*   bidx   = (const int*)d_in[4];
    const float* lnag   = (const float*)d_in[5];
    const float* lnab   = (const float*)d_in[6];
    const float* Wa1    = (const float*)d_in[7];
    const float* ba1    = (const float*)d_in[8];
    const float* Wa2    = (const float*)d_in[9];
    const float* ba2    = (const float*)d_in[10];
    const float* lnng   = (const float*)d_in[11];
    const float* lnnb   = (const float*)d_in[12];
    const float* Wn1    = (const float*)d_in[13];
    const float* bn1    = (const float*)d_in[14];
    const float* Wn2    = (const float*)d_in[15];
    const float* bn2    = (const float*)d_in[16];
    const float* Wnu    = (const float*)d_in[17];

    int N = in_sizes[0] / 3;
    int B = in_sizes[1] / 3;

    unsigned short* wq = (unsigned short*)d_ws;            // NC*FD bf16 = 32 KiB
    float* c  = (float*)((char*)d_ws + NC * FD * 2);       // 128 f32
    float* w2 = c + NC;                                    // 128 f32

    hipMemsetAsync(d_out, 0, (size_t)B * sizeof(float), stream);

    hipLaunchKernelGGL(prep_kernel, dim3(1), dim3(NC), 0, stream,
                       lnag, lnab, Wa1, ba1, Wa2, lnng, lnnb, Wn1, bn1, Wn2, wq, c, w2);

    int blocks = (N + RPB - 1) / RPB;
    hipLaunchKernelGGL(fused_kernel, dim3(blocks), dim3(256), 0, stream,
                       scaler, vec, Wnu, pos, mc, bidx, wq, c, w2, ba2, bn2,
                       (float*)d_out, N);
}